// Round 13
// baseline (308.351 us; speedup 1.0000x reference)
//
#include <hip/hip_runtime.h>
#include <stdint.h>

typedef unsigned short ushort_t;
typedef __attribute__((ext_vector_type(4))) float f32x4;
typedef __attribute__((ext_vector_type(8))) short short8;
typedef __attribute__((ext_vector_type(4))) unsigned short us4;

#define L_SEQ   2048
#define NROWS   8192          // B*L = 4*2048
#define KDIM    1024
#define DINNER  2048
#define NHEADS  32
#define DSTATE  64
#define DCONVD  2176          // D_INNER + 2*D_STATE
#define NPROJ   4256
#define NPROJP  4352          // padded to 17*256
#define LDZX    4352
#define NCHUNK  32            // L / 64

__device__ __forceinline__ float bf2f(ushort_t u) {
    union { uint32_t i; float f; } v; v.i = ((uint32_t)u) << 16; return v.f;
}
__device__ __forceinline__ ushort_t f2bf(float f) {
    uint32_t x = __float_as_uint(f);
    x += 0x7FFFu + ((x >> 16) & 1u);
    return (ushort_t)(x >> 16);
}
__device__ __forceinline__ int swzi(int row, int col) {
    return row * 64 + (col ^ ((row & 7) << 3));
}

// ---------------- fused cast kernel (x, in_proj_w padded, out_proj_w) ----------------
#define NX4 (NROWS * KDIM / 4)      // 2097152
#define NW4 (NPROJP * KDIM / 4)     // 1114112
#define NO4 (KDIM * DINNER / 4)     // 524288
__global__ __launch_bounds__(256) void fused_cast_kernel(
    const float* __restrict__ x, const float* __restrict__ w, const float* __restrict__ ow,
    ushort_t* __restrict__ xbf, ushort_t* __restrict__ wbf, ushort_t* __restrict__ owbf) {
    int i = blockIdx.x * 256 + threadIdx.x;
    if (i < NX4) {
        float4 v = ((const float4*)x)[i];
        ushort4 o;
        o.x = f2bf(v.x); o.y = f2bf(v.y); o.z = f2bf(v.z); o.w = f2bf(v.w);
        ((ushort4*)xbf)[i] = o;
    } else if (i < NX4 + NW4) {
        int j = i - NX4;
        int row = (j * 4) >> 10;
        ushort4 o;
        if (row < NPROJ) {
            float4 v = ((const float4*)w)[j];
            o.x = f2bf(v.x); o.y = f2bf(v.y); o.z = f2bf(v.z); o.w = f2bf(v.w);
        } else { o.x = 0; o.y = 0; o.z = 0; o.w = 0; }
        ((ushort4*)wbf)[j] = o;
    } else if (i < NX4 + NW4 + NO4) {
        int j = i - NX4 - NW4;
        float4 v = ((const float4*)ow)[j];
        ushort4 o;
        o.x = f2bf(v.x); o.y = f2bf(v.y); o.z = f2bf(v.z); o.w = f2bf(v.w);
        ((ushort4*)owbf)[j] = o;
    }
}

__device__ __forceinline__ void async16(const void* g, void* l) {
    __builtin_amdgcn_global_load_lds((const __attribute__((address_space(1))) void*)g,
                                     (__attribute__((address_space(3))) void*)l, 16, 0, 0);
}

// ---------------- BMx256 4-phase GEMM: C[M][N] = A[M][K] * B[N][K]^T ----------------
// 8 waves, BK=64, dbuf LDS, counted vmcnt(2) at q0 (never drains next-tile loads),
// 0-conflict 64-wide swizzle (inverse-swizzled global source, rule #21).
// Per K-tile: 4 phases; q1-q3 issue their ds_reads PRE-barrier (in flight during the
// barrier wait, completed by compiler lgkmcnt before MFMA) — the m201 ordering, now
// combined with the proven swizzle. q0 reads post-barrier (tile-ready fence).
// OUT_BF16 epilogue: LDS-bounce for fully-coalesced 16B/lane stores.
template<int BM, bool OUT_BF16>
__global__ __launch_bounds__(512, 1) void gemm256_kernel(const ushort_t* __restrict__ Ap,
                                                         const ushort_t* __restrict__ Bp,
                                                         void* __restrict__ Cp,
                                                         const int K, const int ldc,
                                                         const int ntn) {
    constexpr int NAH = BM / 128;      // A half-tiles (2 or 1)
    constexpr int FR  = BM / 32;       // per-wave row frags (8 or 4)
    constexpr int FRH = FR / 2;        // frags per phase
    constexpr int NPAN = 2 * (NAH + 2);   // LDS panels of 8192 ushorts
    __shared__ ushort_t ldsAll[NPAN * 8192];
    auto ldsA = [&](int d, int h) { return ldsAll + (size_t)(d * (NAH + 2) + h) * 8192; };
    auto ldsB = [&](int d, int h) { return ldsAll + (size_t)(d * (NAH + 2) + NAH + h) * 8192; };

    const int tid = threadIdx.x;
    const int w = tid >> 6, l = tid & 63;
    const int lr = l & 15, lk = l >> 4;
    const int wm = w >> 2, wn = w & 3;

    const int lin = blockIdx.x;          // gridDim.x % 8 == 0
    const int cpx = gridDim.x >> 3;
    const int swz = (lin & 7) * cpx + (lin >> 3);
    const int nt = swz % ntn, mt = swz / ntn;
    const int m0 = mt * BM, n0 = nt * 256;

    const int row0 = tid >> 3,          c0 = (tid & 7) ^ (row0 & 7);
    const int row1 = (512 + tid) >> 3,  c1 = ((512 + tid) & 7) ^ (row1 & 7);

    const int bcol = wn * 64;
    const int bh = bcol >> 7, bw0 = bcol & 127;

    f32x4 acc[FR][4];
    const f32x4 zero = {0.f, 0.f, 0.f, 0.f};
#pragma unroll
    for (int i = 0; i < FR; ++i)
#pragma unroll
        for (int j = 0; j < 4; ++j) acc[i][j] = zero;

    auto stage = [&](int d_, int isB, int h_, int ktn) {
        const ushort_t* gb = (isB ? Bp + (size_t)(n0 + h_ * 128) * K
                                  : Ap + (size_t)(m0 + h_ * 128) * K) + (size_t)ktn * 64;
        ushort_t* lb = isB ? ldsB(d_, h_) : ldsA(d_, h_);
        async16(gb + (size_t)row0 * K + c0 * 8, lb + w * 512);
        async16(gb + (size_t)row1 * K + c1 * 8, lb + 4096 + w * 512);
    };

#define READS(frh_, ks_, doB_) do {                                                   \
        _Pragma("unroll")                                                             \
        for (int fr = 0; fr < FRH; ++fr) {                                            \
            const int ar = (NAH == 2 ? 0 : wm * 64) + ((frh_) * FRH + fr) * 16 + lr;  \
            af[fr] = *(const short8*)&Ah[ar * 64 + ((((ks_) * 4 + lk) ^ (ar & 7)) << 3)]; \
        }                                                                             \
        if (doB_) {                                                                   \
            _Pragma("unroll")                                                         \
            for (int fc = 0; fc < 4; ++fc) {                                          \
                const int br = bw0 + fc * 16 + lr;                                    \
                bfv[fc] = *(const short8*)&Bh[br * 64 + ((((ks_) * 4 + lk) ^ (br & 7)) << 3)]; \
            }                                                                         \
        }                                                                             \
    } while (0)

#define MFMAS(frh_) do {                                                              \
        __builtin_amdgcn_s_setprio(1);                                                \
        _Pragma("unroll")                                                             \
        for (int fr = 0; fr < FRH; ++fr)                                              \
            _Pragma("unroll")                                                         \
            for (int fc = 0; fc < 4; ++fc)                                            \
                acc[(frh_) * FRH + fr][fc] = __builtin_amdgcn_mfma_f32_16x16x32_bf16( \
                    af[fr], bfv[fc], acc[(frh_) * FRH + fr][fc], 0, 0, 0);            \
        __builtin_amdgcn_s_setprio(0);                                                \
    } while (0)

    // prologue: stage kt=0 fully into dbuf 0 (no wait — q0 of kt=0 fences)
    stage(0, 0, 0, 0); stage(0, 1, 0, 0);
    if (NAH == 2) stage(0, 0, 1, 0);
    stage(0, 1, 1, 0);

    const int NKT = K >> 6;
    for (int kt = 0; kt < NKT; ++kt) {
        const int d = kt & 1;
        const bool more = (kt + 1 < NKT);
        const ushort_t* Ah = (NAH == 2) ? ldsA(d, wm) : ldsA(d, 0);
        const ushort_t* Bh = ldsB(d, bh);
        short8 af[FRH], bfv[4];

        // ---- q0: ks0 frh0 (reads post-barrier: tile-ready fence) ----
        if (more) stage(d ^ 1, 0, 0, kt + 1);     // A h0 of kt+1 (2 loads/thread)
        if (more) asm volatile("s_waitcnt vmcnt(2)" ::: "memory");
        else      asm volatile("s_waitcnt vmcnt(0)" ::: "memory");
        __builtin_amdgcn_s_barrier();
        READS(0, 0, 1);
        MFMAS(0);
        __builtin_amdgcn_s_barrier();

        // ---- q1: ks0 frh1 (reads pre-barrier) ----
        if (more) stage(d ^ 1, 1, 0, kt + 1);     // B h0
        READS(1, 0, 0);
        __builtin_amdgcn_s_barrier();
        MFMAS(1);
        __builtin_amdgcn_s_barrier();

        // ---- q2: ks1 frh0 ----
        if (more && NAH == 2) stage(d ^ 1, 0, 1, kt + 1);   // A h1
        READS(0, 1, 1);
        __builtin_amdgcn_s_barrier();
        MFMAS(0);
        __builtin_amdgcn_s_barrier();

        // ---- q3: ks1 frh1 ----
        if (more) stage(d ^ 1, 1, 1, kt + 1);     // B h1
        READS(1, 1, 0);
        __builtin_amdgcn_s_barrier();
        MFMAS(1);
        __builtin_amdgcn_s_barrier();
    }
#undef READS
#undef MFMAS

    if constexpr (OUT_BF16 && BM == 256) {
        // LDS-bounce epilogue: LDS quiescent (vmcnt(0) at last q0; all reads consumed)
#pragma unroll
        for (int fr2 = 0; fr2 < FR; ++fr2)
#pragma unroll
            for (int fc2 = 0; fc2 < 4; ++fc2) {
                const int lrow = wm * 128 + fr2 * 16 + lk * 4;
                const int lcol = bcol + fc2 * 16 + lr;
#pragma unroll
                for (int r = 0; r < 4; ++r)
                    ldsAll[(lrow + r) * 256 + lcol] = f2bf(acc[fr2][fc2][r]);
            }
        __builtin_amdgcn_s_barrier();
#pragma unroll
        for (int pass = 0; pass < 16; ++pass) {
            const int e = pass * 4096 + tid * 8;
            const int row = e >> 8, col = e & 255;
            short8 v = *(const short8*)&ldsAll[row * 256 + col];
            *(short8*)((ushort_t*)Cp + (size_t)(m0 + row) * ldc + n0 + col) = v;
        }
    } else {
#pragma unroll
        for (int fr2 = 0; fr2 < FR; ++fr2)
#pragma unroll
            for (int fc2 = 0; fc2 < 4; ++fc2) {
                const int col = n0 + bcol + fc2 * 16 + lr;
                const int rowb = m0 + wm * (BM / 2) + fr2 * 16 + lk * 4;
#pragma unroll
                for (int r = 0; r < 4; ++r) {
                    if (OUT_BF16)
                        ((ushort_t*)Cp)[(size_t)(rowb + r) * ldc + col] = f2bf(acc[fr2][fc2][r]);
                    else
                        ((float*)Cp)[(size_t)(rowb + r) * ldc + col] = acc[fr2][fc2][r];
                }
            }
    }
}

// ---------------- conv (4-tap causal) + SiLU, short8-vectorized ----------------
__global__ __launch_bounds__(256) void conv_silu_kernel(const ushort_t* __restrict__ zx,
                                                        const float* __restrict__ conv_w,
                                                        const float* __restrict__ conv_b,
                                                        ushort_t* __restrict__ convout) {
    const int idx = blockIdx.x * 256 + threadIdx.x;   // NROWS * 272
    const int row = idx / 272;
    const int c = (idx - row * 272) * 8;
    const int l = row & (L_SEQ - 1);
    float acc[8];
    {
        const float4* bp = (const float4*)(conv_b + c);
        float4 b0 = bp[0], b1 = bp[1];
        acc[0] = b0.x; acc[1] = b0.y; acc[2] = b0.z; acc[3] = b0.w;
        acc[4] = b1.x; acc[5] = b1.y; acc[6] = b1.z; acc[7] = b1.w;
    }
    float wv[8][4];
    {
        const float4* wp = (const float4*)(conv_w + c * 4);
#pragma unroll
        for (int i = 0; i < 8; ++i) {
            float4 t = wp[i];
            wv[i][0] = t.x; wv[i][1] = t.y; wv[i][2] = t.z; wv[i][3] = t.w;
        }
    }
#pragma unroll
    for (int k = 0; k < 4; ++k) {
        const int ll = l - 3 + k;
        if (ll >= 0) {
            short8 v = *(const short8*)(zx + (size_t)(row - 3 + k) * LDZX + DINNER + c);
#pragma unroll
            for (int i = 0; i < 8; ++i)
                acc[i] += bf2f((ushort_t)v[i]) * wv[i][k];
        }
    }
    short8 o;
#pragma unroll
    for (int i = 0; i < 8; ++i) {
        float s = acc[i] / (1.f + expf(-acc[i]));
        o[i] = (short)f2bf(s);
    }
    *(short8*)(convout + (size_t)row * DCONVD + c) = o;
}

// ---------------- Phase A (MFMA): per-chunk intra output + chunk state G ----------------
// dt = softplus(zx[.,4224+h] + bias) computed inline.
__global__ __launch_bounds__(256) void chunk_intra_kernel(
    const ushort_t* __restrict__ cvb, const ushort_t* __restrict__ zx,
    const float* __restrict__ dt_bias,
    const float* __restrict__ A_log, const float* __restrict__ Dvec,
    ushort_t* __restrict__ ybuf, ushort_t* __restrict__ Gbuf,
    float* __restrict__ expPb)
{
    const int c = blockIdx.x, h = blockIdx.y, b = blockIdx.z;
    const int tid = threadIdx.x;
    const int wv = tid >> 6, lane = tid & 63;
    const int lr = lane & 15, lk = lane >> 4;

    __shared__ __align__(16) ushort_t Cs[4096];  // [t][n] swz
    __shared__ __align__(16) ushort_t Bs[4096];  // [t][n] swz
    __shared__ __align__(16) ushort_t Xt[4096];  // [p][t] swz
    __shared__ __align__(16) ushort_t Ss[4096];  // [i][j] swz (masked S, bf16)
    __shared__ __align__(16) ushort_t Bw[4096];  // [n][t] swz (B^T * w_t)
    __shared__ float sP[64], sdt[64], sWf[64];

    const int t4 = tid >> 2, qq = tid & 3;
    const size_t rowg0 = (size_t)b * L_SEQ + c * 64;
    const ushort_t* rowp = cvb + (rowg0 + t4) * DCONVD;

    short8 rb0 = *(const short8*)(rowp + DINNER + qq * 16);
    short8 rb1 = *(const short8*)(rowp + DINNER + qq * 16 + 8);
    short8 rc0 = *(const short8*)(rowp + DINNER + DSTATE + qq * 16);
    short8 rc1 = *(const short8*)(rowp + DINNER + DSTATE + qq * 16 + 8);
    short8 rx0 = *(const short8*)(rowp + h * 64 + qq * 16);
    short8 rx1 = *(const short8*)(rowp + h * 64 + qq * 16 + 8);

    *(short8*)&Cs[swzi(t4, qq * 16)]     = rc0;
    *(short8*)&Cs[swzi(t4, qq * 16 + 8)] = rc1;
    *(short8*)&Bs[swzi(t4, qq * 16)]     = rb0;
    *(short8*)&Bs[swzi(t4, qq * 16 + 8)] = rb1;
#pragma unroll
    for (int k = 0; k < 8; ++k) {
        Xt[swzi(qq * 16 + k, t4)]     = (ushort_t)rx0[k];
        Xt[swzi(qq * 16 + 8 + k, t4)] = (ushort_t)rx1[k];
    }
    if (tid < 64) {
        float dv = bf2f(zx[(rowg0 + tid) * LDZX + (NPROJ - NHEADS) + h]) + dt_bias[h];
        float dt = (dv > 20.f) ? dv : log1pf(expf(dv));
        float A = -__expf(A_log[h]);
        float P = dt * A;
#pragma unroll
        for (int off = 1; off < 64; off <<= 1) {
            float o = __shfl_up(P, off);
            if (tid >= off) P += o;
        }
        sP[tid] = P;
        sdt[tid] = dt;
        float P63 = __shfl(P, 63);
        sWf[tid] = __expf(P63 - P) * dt;
        expPb[(size_t)(b * NHEADS + h) * L_SEQ + c * 64 + tid] = __expf(P);
    }
    __syncthreads();

    {
        const float w = sWf[t4];
#pragma unroll
        for (int k = 0; k < 8; ++k) {
            Bw[swzi(qq * 16 + k, t4)]     = f2bf(bf2f((ushort_t)rb0[k]) * w);
            Bw[swzi(qq * 16 + 8 + k, t4)] = f2bf(bf2f((ushort_t)rb1[k]) * w);
        }
    }

    // ---- MFMA 1: S = C.B^T ----
    const float Dh = Dvec[h];
    {
        short8 a0 = *(const short8*)&Cs[swzi(wv * 16 + lr, lk * 8)];
        short8 a1 = *(const short8*)&Cs[swzi(wv * 16 + lr, 32 + lk * 8)];
        f32x4 acc[4];
        const f32x4 zero = {0.f, 0.f, 0.f, 0.f};
#pragma unroll
        for (int nj = 0; nj < 4; ++nj) {
            short8 b0 = *(const short8*)&Bs[swzi(nj * 16 + lr, lk * 8)];
            short8 b1 = *(const short8*)&Bs[swzi(nj * 16 + lr, 32 + lk * 8)];
            acc[nj] = __builtin_amdgcn_mfma_f32_16x16x32_bf16(a0, b0, zero, 0, 0, 0);
            acc[nj] = __builtin_amdgcn_mfma_f32_16x16x32_bf16(a1, b1, acc[nj], 0, 0, 0);
        }
#pragma unroll
        for (int r = 0; r < 4; ++r) {
            const int i = wv * 16 + lk * 4 + r;
            const float Pi = sP[i];
#pragma unroll
            for (int nj = 0; nj < 4; ++nj) {
                const int j = nj * 16 + lr;
                float s = 0.f;
                if (j <= i) s = acc[nj][r] * __expf(Pi - sP[j]) * sdt[j];
                if (j == i) s += Dh;
                Ss[swzi(i, j)] = f2bf(s);
            }
        }
    }
    __syncthreads();

    // ---- MFMA 2: Y = S.X -> ybuf ----
    {
        short8 a0 = *(const short8*)&Ss[swzi(wv * 16 + lr, lk * 8)];
        short8 a1 = *(const short8*)&Ss[swzi(wv * 16 + lr, 32 + lk * 8)];
        const f32x4 zero = {0.f, 0.f, 0.f, 0.f};
#pragma unroll
        for (int np = 0; np < 4; ++np) {
            short8 b0 = *(const short8*)&Xt[swzi(np * 16 + lr, lk * 8)];
            short8 b1 = *(const short8*)&Xt[swzi(np * 16 + lr, 32 + lk * 8)];
            f32x4 acc = __builtin_amdgcn_mfma_f32_16x16x32_bf16(a0, b0, zero, 0, 0, 0);
            acc = __builtin_amdgcn_mfma_f32_16x16x32_bf16(a1, b1, acc, 0, 0, 0);
#pragma unroll
            for (int r = 0; r < 4; ++r) {
                const int i = wv * 16 + lk * 4 + r;
                const int p = np * 16 + lr;
                ybuf[(rowg0 + i) * DINNER + (size_t)h * 64 + p] = f2bf(acc[r]);
            }
        }
    }

    // ---- MFMA 3: G^T[p][n] = Xt . Bw^T -> Gbuf ([p][n] layout) ----
    {
        short8 a0 = *(const short8*)&Xt[swzi(wv * 16 + lr, lk * 8)];
        short8 a1 = *(const short8*)&Xt[swzi(wv * 16 + lr, 32 + lk * 8)];
        const f32x4 zero = {0.f, 0.f, 0.f, 0.f};
        const size_t gbase = ((size_t)((b * NHEADS + h) * NCHUNK + c)) << 12;
#pragma unroll
        for (int nt = 0; nt < 4; ++nt) {
            short8 b0 = *(const short8*)&Bw[swzi(nt * 16 + lr, lk * 8)];
            short8 b1 = *(const short8*)&Bw[swzi(nt * 16 + lr, 32 + lk * 8)];
            f32x4 acc = __builtin_amdgcn_mfma_f32_16x16x32_bf16(a0, b0, zero, 0, 0, 0);
            acc = __builtin_amdgcn_mfma_f32_16x16x32_bf16(a1, b1, acc, 0, 0, 0);
#pragma unroll
            for (int r = 0; r < 4; ++r) {
                const int p = wv * 16 + lk * 4 + r;
                const int n = nt * 16 + lr;
                Gbuf[gbase + p * 64 + n] = f2bf(acc[r]);
            }
        }
    }
}

// ---------------- Phase B1: elementwise chunk-state scan (in-place G -> hstates) ----------------
__global__ __launch_bounds__(256) void state_scan_kernel(
    ushort_t* __restrict__ GH, const float* __restrict__ expPb)
{
    const int half = blockIdx.x, h = blockIdx.y, b = blockIdx.z;
    const int bh = b * NHEADS + h;
    const int e0 = half * 2048 + threadIdx.x * 8;
    ushort_t* base = GH + ((size_t)bh << 17);
    const float* ep = expPb + (size_t)bh * L_SEQ;

    float hr[8];
#pragma unroll
    for (int k = 0; k < 8; ++k) hr[k] = 0.f;

    short8 g = *(const short8*)(base + e0);
    float Ec = ep[63];
    for (int c = 0; c < NCHUNK; ++c) {
        short8 gn = g; float En = 0.f;
        if (c + 1 < NCHUNK) {
            gn = *(const short8*)(base + ((size_t)(c + 1) << 12) + e0);
            En = ep[(c + 1) * 64 + 63];
        }
        short8 o;
#pragma unroll
        for (int k = 0; k < 8; ++k) o[k] = (short)f2bf(hr[k]);
        *(short8*)(base + ((size_t)c << 12) + e0) = o;
#pragma unroll
        for (int k = 0; k < 8; ++k) hr[k] = hr[k] * Ec + bf2f((ushort_t)g[k]);
        g = gn; Ec = En;
    }
}

// ---------------- Phase B2 (MFMA): y_inter[t][p] = expP[t] * sum_n C[t][n] h[n][p] ----------------
__global__ __launch_bounds__(256) void y_inter_kernel(
    const ushort_t* __restrict__ cvb, const float* __restrict__ expPb,
    const ushort_t* __restrict__ hst, ushort_t* __restrict__ ybuf)
{
    const int c = blockIdx.x + 1, h = blockIdx.y, b = blockIdx.z;
    const int tid = threadIdx.x;
    const int wv = tid >> 6, lane = tid & 63;
    const int lr = lane & 15, lk = lane >> 4;
    const int bh = b * NHEADS + h;

    __shared__ __align__(16) ushort_t Cs[4096];  // [t][n] swz
    __shared__ __align__(16) ushort_t Hp[4096];  // [p][n] swz
    __shared__ float sEp[64];

    const int t4 = tid >> 2, qq = tid & 3;
    const size_t rowg0 = (size_t)b * L_SEQ + c * 64;
    {
        const ushort_t* rp = cvb + (rowg0 + t4) * DCONVD + DINNER + DSTATE + qq * 16;
        *(short8*)&Cs[swzi(t4, qq * 16)]     = *(const short8*)rp;
        *(short8*)&Cs[swzi(t4, qq * 16 + 8)] = *(const short8*)(rp + 8);
        const ushort_t* hr = hst + (((size_t)(bh * NCHUNK + c)) << 12) + t4 * 64 + qq * 16;
        *(short8*)&Hp[swzi(t4, qq * 16)]     = *(const short8*)hr;
        *(short8*)&Hp[swzi(t4, qq * 16 + 8)] = *(const short8*)(hr + 8);
    }
    if (tid < 64) sEp[tid] = expPb[(size_t)bh * L_SEQ + c * 64 + tid];
    __syncthreads();

    short8 a0 = *(const short8*)&Cs[swzi(wv * 16 + lr, lk * 8)];
    short8 a1 = *(const short8*)&Cs[swzi(wv * 16 + lr, 32 + lk * 8)];
    const f32x4 zero = {0.f, 0.f, 0.f, 0.f};
#pragma unroll
    for (int np = 0; np < 4; ++np) {
        short8 b0 = *(const short8*)&Hp[swzi(np * 16 + lr, lk * 8)];
        short8 b1 = *(const short8*)&Hp[swzi(np * 16 + lr, 32 + lk * 8)];
        f32x4 acc = __builtin_amdgcn_mfma_f32_16x16x32_bf16(a0, b0, zero, 0, 0, 0);
        acc = __builtin_amdgcn_mfma_f32_16x16x32_bf16(a1, b1, acc, 0, 0, 0);
#pragma unroll
        for (int r = 0; r < 4; ++r) {
            const int t = wv * 16 + lk * 4 + r;
            const int p = np * 16 + lr;
            ushort_t* yp = &ybuf[(rowg0 + t) * DINNER + (size_t)h * 64 + p];
            *yp = f2bf(bf2f(*yp) + acc[r] * sEp[t]);
        }
    }
}

// ---------------- gate (y * silu(z)) + RMSNorm -> bf16 ----------------
__global__ __launch_bounds__(256) void gatenorm_kernel(const ushort_t* __restrict__ ybuf,
                                                       const ushort_t* __restrict__ zx,
                                                       const float* __restrict__ norm_w,
                                                       ushort_t* __restrict__ gbuf) {
    const int row = blockIdx.x;
    const int tid = threadIdx.x;
    short8 yv = *(const short8*)(ybuf + (size_t)row * DINNER + tid * 8);
    short8 zv = *(const short8*)(zx + (size_t)row * LDZX + tid * 8);
    float g[8];
    float ss = 0.f;
#pragma unroll
    for (int i = 0; i < 8; ++i) {
        float y = bf2f((ushort_t)yv[i]);
        float z = bf2f((ushort_t)zv[i]);
        float sz = z / (1.f + expf(-z));
        float gg = y * sz;
        g[i] = gg;
        ss += gg * gg;
    }
#pragma unroll
    for (int o = 32; o > 0; o >>= 1) ss += __shfl_xor(ss, o);
    __shared__ float wsum[4];
    if ((tid & 63) == 0) wsum[tid >> 6] = ss;
    __syncthreads();
    float tot = wsum[0] + wsum[1] + wsum[2] + wsum[3];
    float scale = rsqrtf(tot * (1.0f / (float)DINNER) + 1e-5f);
    short8 o8;
#pragma unroll
    for (int i = 0; i < 8; ++i)
        o8[i] = (short)f2bf(g[i] * scale * norm_w[tid * 8 + i]);
    *(short8*)(gbuf + (size_t)row * DINNER + tid * 8) = o8;
}

// ---------------- launch ----------------
extern "C" void kernel_launch(void* const* d_in, const int* in_sizes, int n_in,
                              void* d_out, int out_size, void* d_ws, size_t ws_size,
                              hipStream_t stream) {
    const float* x          = (const float*)d_in[0];
    const float* in_proj_w  = (const float*)d_in[1];
    const float* conv_w     = (const float*)d_in[2];
    const float* conv_b     = (const float*)d_in[3];
    const float* dt_bias    = (const float*)d_in[4];
    const float* A_log      = (const float*)d_in[5];
    const float* Dvec       = (const float*)d_in[6];
    const float* norm_w     = (const float*)d_in[7];
    const float* out_proj_w = (const float*)d_in[8];
    float* out = (float*)d_out;

    char* ws = (char*)d_ws;
    size_t off = 0;
    ushort_t* owbf  = (ushort_t*)(ws + off); off += (size_t)KDIM * DINNER * 2;     // 4.2 MB
    ushort_t* zx    = (ushort_t*)(ws + off); off += (size_t)NROWS * LDZX * 2;      // 71.3 MB
    ushort_t* cvb   = (ushort_t*)(ws + off); off += (size_t)NROWS * DCONVD * 2;    // 35.7 MB
    float*    expPb = (float*)(ws + off);    off += (size_t)128 * L_SEQ * 4;       // 1.05 MB
    ushort_t* ybuf  = (ushort_t*)(ws + off); off += (size_t)NROWS * DINNER * 2;    // 33.6 MB
    char* tail = ws + off;
    ushort_t* xbf  = (ushort_t*)tail;
    ushort_t* wbf  = (ushort_t*)(tail + (size_t)NROWS * KDIM * 2);
    ushort_t* Gbuf = (ushort_t*)tail;
    ushort_t* gbuf = (ushort_t*)tail;

    // fused casts (x -> xbf, in_proj_w -> wbf padded, out_proj_w -> owbf)
    fused_cast_kernel<<<(NX4 + NW4 + NO4) / 256, 256, 0, stream>>>(
        x, in_proj_w, out_proj_w, xbf, wbf, owbf);

    // in-proj GEMM: zx[8192][4352] (bf16), 256x256 4-phase + LDS-bounce epilogue
    gemm256_kernel<256, true><<<544, 512, 0, stream>>>(xbf, wbf, zx, KDIM, LDZX, 17);

    // conv + silu (short8-vectorized)
    conv_silu_kernel<<<NROWS * 272 / 256, 256, 0, stream>>>(zx, conv_w, conv_b, cvb);

    // chunked scan: phase A (parallel, MFMA; dt softplus fused)
    chunk_intra_kernel<<<dim3(NCHUNK, NHEADS, 4), 256, 0, stream>>>(
        cvb, zx, dt_bias, A_log, Dvec, ybuf, Gbuf, expPb);
    // phase B1: elementwise state scan (in-place G -> hstates)
    state_scan_kernel<<<dim3(2, NHEADS, 4), 256, 0, stream>>>(Gbuf, expPb);
    // phase B2: inter-chunk contribution (parallel MFMA matmuls)
    y_inter_kernel<<<dim3(NCHUNK - 1, NHEADS, 4), 256, 0, stream>>>(
        cvb, expPb, Gbuf, ybuf);

    // gate + rmsnorm
    gatenorm_kernel<<<NROWS, 256, 0, stream>>>(ybuf, zx, norm_w, gbuf);

    // out-proj GEMM -> d_out (f32), 128x256 4-phase  (grid 256 = 8*32, 1 round)
    gemm256_kernel<128, false><<<256, 512, 0, stream>>>(gbuf, owbf, out, DINNER, KDIM, 4);
}

// Round 14
// 297.458 us; speedup vs baseline: 1.0366x; 1.0366x over previous
//
#include <hip/hip_runtime.h>
#include <stdint.h>

typedef unsigned short ushort_t;
typedef __attribute__((ext_vector_type(4))) float f32x4;
typedef __attribute__((ext_vector_type(8))) short short8;
typedef __attribute__((ext_vector_type(4))) unsigned short us4;

#define L_SEQ   2048
#define NROWS   8192          // B*L = 4*2048
#define KDIM    1024
#define DINNER  2048
#define NHEADS  32
#define DSTATE  64
#define DCONVD  2176          // D_INNER + 2*D_STATE
#define NPROJ   4256
#define NPROJP  4352          // padded to 17*256
#define LDZX    4352
#define NCHUNK  32            // L / 64

__device__ __forceinline__ float bf2f(ushort_t u) {
    union { uint32_t i; float f; } v; v.i = ((uint32_t)u) << 16; return v.f;
}
__device__ __forceinline__ ushort_t f2bf(float f) {
    uint32_t x = __float_as_uint(f);
    x += 0x7FFFu + ((x >> 16) & 1u);
    return (ushort_t)(x >> 16);
}
__device__ __forceinline__ int swzi(int row, int col) {
    return row * 64 + (col ^ ((row & 7) << 3));
}

// ---------------- fused cast kernel (x, in_proj_w padded, out_proj_w) ----------------
#define NX4 (NROWS * KDIM / 4)      // 2097152
#define NW4 (NPROJP * KDIM / 4)     // 1114112
#define NO4 (KDIM * DINNER / 4)     // 524288
__global__ __launch_bounds__(256) void fused_cast_kernel(
    const float* __restrict__ x, const float* __restrict__ w, const float* __restrict__ ow,
    ushort_t* __restrict__ xbf, ushort_t* __restrict__ wbf, ushort_t* __restrict__ owbf) {
    int i = blockIdx.x * 256 + threadIdx.x;
    if (i < NX4) {
        float4 v = ((const float4*)x)[i];
        ushort4 o;
        o.x = f2bf(v.x); o.y = f2bf(v.y); o.z = f2bf(v.z); o.w = f2bf(v.w);
        ((ushort4*)xbf)[i] = o;
    } else if (i < NX4 + NW4) {
        int j = i - NX4;
        int row = (j * 4) >> 10;
        ushort4 o;
        if (row < NPROJ) {
            float4 v = ((const float4*)w)[j];
            o.x = f2bf(v.x); o.y = f2bf(v.y); o.z = f2bf(v.z); o.w = f2bf(v.w);
        } else { o.x = 0; o.y = 0; o.z = 0; o.w = 0; }
        ((ushort4*)wbf)[j] = o;
    } else if (i < NX4 + NW4 + NO4) {
        int j = i - NX4 - NW4;
        float4 v = ((const float4*)ow)[j];
        ushort4 o;
        o.x = f2bf(v.x); o.y = f2bf(v.y); o.z = f2bf(v.z); o.w = f2bf(v.w);
        ((ushort4*)owbf)[j] = o;
    }
}

__device__ __forceinline__ void async16(const void* g, void* l) {
    __builtin_amdgcn_global_load_lds((const __attribute__((address_space(1))) void*)g,
                                     (__attribute__((address_space(3))) void*)l, 16, 0, 0);
}

// ---------------- BMx256 2-phase GEMM (R12 optimum): C[M][N] = A[M][K] * B[N][K]^T ----
// 8 waves, BK=64, dbuf LDS, counted vmcnt(4) (never 0 mid-loop), 0-conflict 64-wide
// swizzle via inverse-swizzled global source + swizzled ds_read (rule #21).
// BM=256: wave-tile 128x64 (FR=8), 128 KiB LDS.  BM=128: 64x64 (FR=4), 96 KiB.
// OUT_BF16 epilogue: LDS-bounce (reuse the 128 KiB as 256x256 bf16 tile) for
// fully-coalesced 16B/lane stores (raw fragment stores = 32B runs, ~2x sector waste).
template<int BM, bool OUT_BF16>
__global__ __launch_bounds__(512, 1) void gemm256_kernel(const ushort_t* __restrict__ Ap,
                                                         const ushort_t* __restrict__ Bp,
                                                         void* __restrict__ Cp,
                                                         const int K, const int ldc,
                                                         const int ntn) {
    constexpr int NAH = BM / 128;      // A half-tiles (2 or 1)
    constexpr int FR  = BM / 32;       // per-wave row frags (8 or 4)
    constexpr int NPAN = 2 * (NAH + 2);   // LDS panels of 8192 ushorts
    __shared__ ushort_t ldsAll[NPAN * 8192];
    auto ldsA = [&](int d, int h) { return ldsAll + (size_t)(d * (NAH + 2) + h) * 8192; };
    auto ldsB = [&](int d, int h) { return ldsAll + (size_t)(d * (NAH + 2) + NAH + h) * 8192; };

    const int tid = threadIdx.x;
    const int w = tid >> 6, l = tid & 63;
    const int lr = l & 15, lk = l >> 4;
    const int wm = w >> 2, wn = w & 3;

    const int lin = blockIdx.x;          // gridDim.x % 8 == 0
    const int cpx = gridDim.x >> 3;
    const int swz = (lin & 7) * cpx + (lin >> 3);
    const int nt = swz % ntn, mt = swz / ntn;
    const int m0 = mt * BM, n0 = nt * 256;

    const int row0 = tid >> 3,          c0 = (tid & 7) ^ (row0 & 7);
    const int row1 = (512 + tid) >> 3,  c1 = ((512 + tid) & 7) ^ (row1 & 7);

    const int bcol = wn * 64;
    const int bh = bcol >> 7, bw0 = bcol & 127;

    f32x4 acc[FR][4];
    const f32x4 zero = {0.f, 0.f, 0.f, 0.f};
#pragma unroll
    for (int i = 0; i < FR; ++i)
#pragma unroll
        for (int j = 0; j < 4; ++j) acc[i][j] = zero;

    auto stage = [&](int d_, int isB, int h_, int ktn) {
        const ushort_t* gb = (isB ? Bp + (size_t)(n0 + h_ * 128) * K
                                  : Ap + (size_t)(m0 + h_ * 128) * K) + (size_t)ktn * 64;
        ushort_t* lb = isB ? ldsB(d_, h_) : ldsA(d_, h_);
        async16(gb + (size_t)row0 * K + c0 * 8, lb + w * 512);
        async16(gb + (size_t)row1 * K + c1 * 8, lb + 4096 + w * 512);
    };

#define COMPUTE_KS(ks_) do {                                                          \
        short8 af[FR], bfv[4];                                                        \
        _Pragma("unroll")                                                             \
        for (int fr = 0; fr < FR; ++fr) {                                             \
            const int ar = (NAH == 2 ? 0 : wm * 64) + fr * 16 + lr;                   \
            af[fr] = *(const short8*)&Ah[ar * 64 + ((((ks_) * 4 + lk) ^ (ar & 7)) << 3)]; \
        }                                                                             \
        _Pragma("unroll")                                                             \
        for (int fc = 0; fc < 4; ++fc) {                                              \
            const int br = bw0 + fc * 16 + lr;                                        \
            bfv[fc] = *(const short8*)&Bh[br * 64 + ((((ks_) * 4 + lk) ^ (br & 7)) << 3)]; \
        }                                                                             \
        __builtin_amdgcn_s_setprio(1);                                                \
        _Pragma("unroll")                                                             \
        for (int fr = 0; fr < FR; ++fr)                                               \
            _Pragma("unroll")                                                         \
            for (int fc = 0; fc < 4; ++fc)                                            \
                acc[fr][fc] = __builtin_amdgcn_mfma_f32_16x16x32_bf16(                \
                    af[fr], bfv[fc], acc[fr][fc], 0, 0, 0);                           \
        __builtin_amdgcn_s_setprio(0);                                                \
    } while (0)

    // prologue: stage kt=0 fully into dbuf 0
    stage(0, 0, 0, 0); stage(0, 1, 0, 0);
    if (NAH == 2) stage(0, 0, 1, 0);
    stage(0, 1, 1, 0);

    const int NKT = K >> 6;
    for (int kt = 0; kt < NKT; ++kt) {
        const int d = kt & 1;
        const bool more = (kt + 1 < NKT);
        const ushort_t* Ah = (NAH == 2) ? ldsA(d, wm) : ldsA(d, 0);
        const ushort_t* Bh = ldsB(d, bh);

        // leading stages of next tile (A h0, B h0), then wait current tile landed
        if (more) { stage(d ^ 1, 0, 0, kt + 1); stage(d ^ 1, 1, 0, kt + 1); }
        if (more) asm volatile("s_waitcnt vmcnt(4)" ::: "memory");
        else      asm volatile("s_waitcnt vmcnt(0)" ::: "memory");
        __builtin_amdgcn_s_barrier();

        COMPUTE_KS(0);

        // late stages of next tile (A h1 if any, B h1) — overlap ks0 MFMA / ks1 reads
        if (more) { if (NAH == 2) stage(d ^ 1, 0, 1, kt + 1); stage(d ^ 1, 1, 1, kt + 1); }

        COMPUTE_KS(1);

        __builtin_amdgcn_s_barrier();
    }
#undef COMPUTE_KS

    if constexpr (OUT_BF16 && BM == 256) {
        // LDS-bounce epilogue: after the loop's final barrier LDS is quiescent
        // (last tile's reads consumed pre-barrier; vmcnt(0) drained at last iter).
#pragma unroll
        for (int fr2 = 0; fr2 < FR; ++fr2)
#pragma unroll
            for (int fc2 = 0; fc2 < 4; ++fc2) {
                const int lrow = wm * 128 + fr2 * 16 + lk * 4;
                const int lcol = bcol + fc2 * 16 + lr;
#pragma unroll
                for (int r = 0; r < 4; ++r)
                    ldsAll[(lrow + r) * 256 + lcol] = f2bf(acc[fr2][fc2][r]);
            }
        __builtin_amdgcn_s_barrier();
#pragma unroll
        for (int pass = 0; pass < 16; ++pass) {
            const int e = pass * 4096 + tid * 8;
            const int row = e >> 8, col = e & 255;
            short8 v = *(const short8*)&ldsAll[row * 256 + col];
            *(short8*)((ushort_t*)Cp + (size_t)(m0 + row) * ldc + n0 + col) = v;
        }
    } else {
#pragma unroll
        for (int fr2 = 0; fr2 < FR; ++fr2)
#pragma unroll
            for (int fc2 = 0; fc2 < 4; ++fc2) {
                const int col = n0 + bcol + fc2 * 16 + lr;
                const int rowb = m0 + wm * (BM / 2) + fr2 * 16 + lk * 4;
#pragma unroll
                for (int r = 0; r < 4; ++r) {
                    if (OUT_BF16)
                        ((ushort_t*)Cp)[(size_t)(rowb + r) * ldc + col] = f2bf(acc[fr2][fc2][r]);
                    else
                        ((float*)Cp)[(size_t)(rowb + r) * ldc + col] = acc[fr2][fc2][r];
                }
            }
    }
}

// ---------------- conv (4-tap causal) + SiLU, short8-vectorized ----------------
__global__ __launch_bounds__(256) void conv_silu_kernel(const ushort_t* __restrict__ zx,
                                                        const float* __restrict__ conv_w,
                                                        const float* __restrict__ conv_b,
                                                        ushort_t* __restrict__ convout) {
    const int idx = blockIdx.x * 256 + threadIdx.x;   // NROWS * 272
    const int row = idx / 272;
    const int c = (idx - row * 272) * 8;
    const int l = row & (L_SEQ - 1);
    float acc[8];
    {
        const float4* bp = (const float4*)(conv_b + c);
        float4 b0 = bp[0], b1 = bp[1];
        acc[0] = b0.x; acc[1] = b0.y; acc[2] = b0.z; acc[3] = b0.w;
        acc[4] = b1.x; acc[5] = b1.y; acc[6] = b1.z; acc[7] = b1.w;
    }
    float wv[8][4];
    {
        const float4* wp = (const float4*)(conv_w + c * 4);
#pragma unroll
        for (int i = 0; i < 8; ++i) {
            float4 t = wp[i];
            wv[i][0] = t.x; wv[i][1] = t.y; wv[i][2] = t.z; wv[i][3] = t.w;
        }
    }
#pragma unroll
    for (int k = 0; k < 4; ++k) {
        const int ll = l - 3 + k;
        if (ll >= 0) {
            short8 v = *(const short8*)(zx + (size_t)(row - 3 + k) * LDZX + DINNER + c);
#pragma unroll
            for (int i = 0; i < 8; ++i)
                acc[i] += bf2f((ushort_t)v[i]) * wv[i][k];
        }
    }
    short8 o;
#pragma unroll
    for (int i = 0; i < 8; ++i) {
        float s = acc[i] / (1.f + expf(-acc[i]));
        o[i] = (short)f2bf(s);
    }
    *(short8*)(convout + (size_t)row * DCONVD + c) = o;
}

// ---------------- Phase A (MFMA): per-chunk intra output + chunk state G ----------------
// dt = softplus(zx[.,4224+h] + bias) computed inline.
__global__ __launch_bounds__(256) void chunk_intra_kernel(
    const ushort_t* __restrict__ cvb, const ushort_t* __restrict__ zx,
    const float* __restrict__ dt_bias,
    const float* __restrict__ A_log, const float* __restrict__ Dvec,
    ushort_t* __restrict__ ybuf, ushort_t* __restrict__ Gbuf,
    float* __restrict__ expPb)
{
    const int c = blockIdx.x, h = blockIdx.y, b = blockIdx.z;
    const int tid = threadIdx.x;
    const int wv = tid >> 6, lane = tid & 63;
    const int lr = lane & 15, lk = lane >> 4;

    __shared__ __align__(16) ushort_t Cs[4096];  // [t][n] swz
    __shared__ __align__(16) ushort_t Bs[4096];  // [t][n] swz
    __shared__ __align__(16) ushort_t Xt[4096];  // [p][t] swz
    __shared__ __align__(16) ushort_t Ss[4096];  // [i][j] swz (masked S, bf16)
    __shared__ __align__(16) ushort_t Bw[4096];  // [n][t] swz (B^T * w_t)
    __shared__ float sP[64], sdt[64], sWf[64];

    const int t4 = tid >> 2, qq = tid & 3;
    const size_t rowg0 = (size_t)b * L_SEQ + c * 64;
    const ushort_t* rowp = cvb + (rowg0 + t4) * DCONVD;

    short8 rb0 = *(const short8*)(rowp + DINNER + qq * 16);
    short8 rb1 = *(const short8*)(rowp + DINNER + qq * 16 + 8);
    short8 rc0 = *(const short8*)(rowp + DINNER + DSTATE + qq * 16);
    short8 rc1 = *(const short8*)(rowp + DINNER + DSTATE + qq * 16 + 8);
    short8 rx0 = *(const short8*)(rowp + h * 64 + qq * 16);
    short8 rx1 = *(const short8*)(rowp + h * 64 + qq * 16 + 8);

    *(short8*)&Cs[swzi(t4, qq * 16)]     = rc0;
    *(short8*)&Cs[swzi(t4, qq * 16 + 8)] = rc1;
    *(short8*)&Bs[swzi(t4, qq * 16)]     = rb0;
    *(short8*)&Bs[swzi(t4, qq * 16 + 8)] = rb1;
#pragma unroll
    for (int k = 0; k < 8; ++k) {
        Xt[swzi(qq * 16 + k, t4)]     = (ushort_t)rx0[k];
        Xt[swzi(qq * 16 + 8 + k, t4)] = (ushort_t)rx1[k];
    }
    if (tid < 64) {
        float dv = bf2f(zx[(rowg0 + tid) * LDZX + (NPROJ - NHEADS) + h]) + dt_bias[h];
        float dt = (dv > 20.f) ? dv : log1pf(expf(dv));
        float A = -__expf(A_log[h]);
        float P = dt * A;
#pragma unroll
        for (int off = 1; off < 64; off <<= 1) {
            float o = __shfl_up(P, off);
            if (tid >= off) P += o;
        }
        sP[tid] = P;
        sdt[tid] = dt;
        float P63 = __shfl(P, 63);
        sWf[tid] = __expf(P63 - P) * dt;
        expPb[(size_t)(b * NHEADS + h) * L_SEQ + c * 64 + tid] = __expf(P);
    }
    __syncthreads();

    {
        const float w = sWf[t4];
#pragma unroll
        for (int k = 0; k < 8; ++k) {
            Bw[swzi(qq * 16 + k, t4)]     = f2bf(bf2f((ushort_t)rb0[k]) * w);
            Bw[swzi(qq * 16 + 8 + k, t4)] = f2bf(bf2f((ushort_t)rb1[k]) * w);
        }
    }

    // ---- MFMA 1: S = C.B^T ----
    const float Dh = Dvec[h];
    {
        short8 a0 = *(const short8*)&Cs[swzi(wv * 16 + lr, lk * 8)];
        short8 a1 = *(const short8*)&Cs[swzi(wv * 16 + lr, 32 + lk * 8)];
        f32x4 acc[4];
        const f32x4 zero = {0.f, 0.f, 0.f, 0.f};
#pragma unroll
        for (int nj = 0; nj < 4; ++nj) {
            short8 b0 = *(const short8*)&Bs[swzi(nj * 16 + lr, lk * 8)];
            short8 b1 = *(const short8*)&Bs[swzi(nj * 16 + lr, 32 + lk * 8)];
            acc[nj] = __builtin_amdgcn_mfma_f32_16x16x32_bf16(a0, b0, zero, 0, 0, 0);
            acc[nj] = __builtin_amdgcn_mfma_f32_16x16x32_bf16(a1, b1, acc[nj], 0, 0, 0);
        }
#pragma unroll
        for (int r = 0; r < 4; ++r) {
            const int i = wv * 16 + lk * 4 + r;
            const float Pi = sP[i];
#pragma unroll
            for (int nj = 0; nj < 4; ++nj) {
                const int j = nj * 16 + lr;
                float s = 0.f;
                if (j <= i) s = acc[nj][r] * __expf(Pi - sP[j]) * sdt[j];
                if (j == i) s += Dh;
                Ss[swzi(i, j)] = f2bf(s);
            }
        }
    }
    __syncthreads();

    // ---- MFMA 2: Y = S.X -> ybuf ----
    {
        short8 a0 = *(const short8*)&Ss[swzi(wv * 16 + lr, lk * 8)];
        short8 a1 = *(const short8*)&Ss[swzi(wv * 16 + lr, 32 + lk * 8)];
        const f32x4 zero = {0.f, 0.f, 0.f, 0.f};
#pragma unroll
        for (int np = 0; np < 4; ++np) {
            short8 b0 = *(const short8*)&Xt[swzi(np * 16 + lr, lk * 8)];
            short8 b1 = *(const short8*)&Xt[swzi(np * 16 + lr, 32 + lk * 8)];
            f32x4 acc = __builtin_amdgcn_mfma_f32_16x16x32_bf16(a0, b0, zero, 0, 0, 0);
            acc = __builtin_amdgcn_mfma_f32_16x16x32_bf16(a1, b1, acc, 0, 0, 0);
#pragma unroll
            for (int r = 0; r < 4; ++r) {
                const int i = wv * 16 + lk * 4 + r;
                const int p = np * 16 + lr;
                ybuf[(rowg0 + i) * DINNER + (size_t)h * 64 + p] = f2bf(acc[r]);
            }
        }
    }

    // ---- MFMA 3: G^T[p][n] = Xt . Bw^T -> Gbuf ([p][n] layout) ----
    {
        short8 a0 = *(const short8*)&Xt[swzi(wv * 16 + lr, lk * 8)];
        short8 a1 = *(const short8*)&Xt[swzi(wv * 16 + lr, 32 + lk * 8)];
        const f32x4 zero = {0.f, 0.f, 0.f, 0.f};
        const size_t gbase = ((size_t)((b * NHEADS + h) * NCHUNK + c)) << 12;
#pragma unroll
        for (int nt = 0; nt < 4; ++nt) {
            short8 b0 = *(const short8*)&Bw[swzi(nt * 16 + lr, lk * 8)];
            short8 b1 = *(const short8*)&Bw[swzi(nt * 16 + lr, 32 + lk * 8)];
            f32x4 acc = __builtin_amdgcn_mfma_f32_16x16x32_bf16(a0, b0, zero, 0, 0, 0);
            acc = __builtin_amdgcn_mfma_f32_16x16x32_bf16(a1, b1, acc, 0, 0, 0);
#pragma unroll
            for (int r = 0; r < 4; ++r) {
                const int p = wv * 16 + lk * 4 + r;
                const int n = nt * 16 + lr;
                Gbuf[gbase + p * 64 + n] = f2bf(acc[r]);
            }
        }
    }
}

// ---------------- Phase B1: elementwise chunk-state scan (in-place G -> hstates) ----------------
__global__ __launch_bounds__(256) void state_scan_kernel(
    ushort_t* __restrict__ GH, const float* __restrict__ expPb)
{
    const int half = blockIdx.x, h = blockIdx.y, b = blockIdx.z;
    const int bh = b * NHEADS + h;
    const int e0 = half * 2048 + threadIdx.x * 8;
    ushort_t* base = GH + ((size_t)bh << 17);
    const float* ep = expPb + (size_t)bh * L_SEQ;

    float hr[8];
#pragma unroll
    for (int k = 0; k < 8; ++k) hr[k] = 0.f;

    short8 g = *(const short8*)(base + e0);
    float Ec = ep[63];
    for (int c = 0; c < NCHUNK; ++c) {
        short8 gn = g; float En = 0.f;
        if (c + 1 < NCHUNK) {
            gn = *(const short8*)(base + ((size_t)(c + 1) << 12) + e0);
            En = ep[(c + 1) * 64 + 63];
        }
        short8 o;
#pragma unroll
        for (int k = 0; k < 8; ++k) o[k] = (short)f2bf(hr[k]);
        *(short8*)(base + ((size_t)c << 12) + e0) = o;
#pragma unroll
        for (int k = 0; k < 8; ++k) hr[k] = hr[k] * Ec + bf2f((ushort_t)g[k]);
        g = gn; Ec = En;
    }
}

// ---------------- Phase B2 (MFMA): y_inter[t][p] = expP[t] * sum_n C[t][n] h[n][p] ----------------
__global__ __launch_bounds__(256) void y_inter_kernel(
    const ushort_t* __restrict__ cvb, const float* __restrict__ expPb,
    const ushort_t* __restrict__ hst, ushort_t* __restrict__ ybuf)
{
    const int c = blockIdx.x + 1, h = blockIdx.y, b = blockIdx.z;
    const int tid = threadIdx.x;
    const int wv = tid >> 6, lane = tid & 63;
    const int lr = lane & 15, lk = lane >> 4;
    const int bh = b * NHEADS + h;

    __shared__ __align__(16) ushort_t Cs[4096];  // [t][n] swz
    __shared__ __align__(16) ushort_t Hp[4096];  // [p][n] swz
    __shared__ float sEp[64];

    const int t4 = tid >> 2, qq = tid & 3;
    const size_t rowg0 = (size_t)b * L_SEQ + c * 64;
    {
        const ushort_t* rp = cvb + (rowg0 + t4) * DCONVD + DINNER + DSTATE + qq * 16;
        *(short8*)&Cs[swzi(t4, qq * 16)]     = *(const short8*)rp;
        *(short8*)&Cs[swzi(t4, qq * 16 + 8)] = *(const short8*)(rp + 8);
        const ushort_t* hr = hst + (((size_t)(bh * NCHUNK + c)) << 12) + t4 * 64 + qq * 16;
        *(short8*)&Hp[swzi(t4, qq * 16)]     = *(const short8*)hr;
        *(short8*)&Hp[swzi(t4, qq * 16 + 8)] = *(const short8*)(hr + 8);
    }
    if (tid < 64) sEp[tid] = expPb[(size_t)bh * L_SEQ + c * 64 + tid];
    __syncthreads();

    short8 a0 = *(const short8*)&Cs[swzi(wv * 16 + lr, lk * 8)];
    short8 a1 = *(const short8*)&Cs[swzi(wv * 16 + lr, 32 + lk * 8)];
    const f32x4 zero = {0.f, 0.f, 0.f, 0.f};
#pragma unroll
    for (int np = 0; np < 4; ++np) {
        short8 b0 = *(const short8*)&Hp[swzi(np * 16 + lr, lk * 8)];
        short8 b1 = *(const short8*)&Hp[swzi(np * 16 + lr, 32 + lk * 8)];
        f32x4 acc = __builtin_amdgcn_mfma_f32_16x16x32_bf16(a0, b0, zero, 0, 0, 0);
        acc = __builtin_amdgcn_mfma_f32_16x16x32_bf16(a1, b1, acc, 0, 0, 0);
#pragma unroll
        for (int r = 0; r < 4; ++r) {
            const int t = wv * 16 + lk * 4 + r;
            const int p = np * 16 + lr;
            ushort_t* yp = &ybuf[(rowg0 + t) * DINNER + (size_t)h * 64 + p];
            *yp = f2bf(bf2f(*yp) + acc[r] * sEp[t]);
        }
    }
}

// ---------------- gate (y * silu(z)) + RMSNorm -> bf16 ----------------
__global__ __launch_bounds__(256) void gatenorm_kernel(const ushort_t* __restrict__ ybuf,
                                                       const ushort_t* __restrict__ zx,
                                                       const float* __restrict__ norm_w,
                                                       ushort_t* __restrict__ gbuf) {
    const int row = blockIdx.x;
    const int tid = threadIdx.x;
    short8 yv = *(const short8*)(ybuf + (size_t)row * DINNER + tid * 8);
    short8 zv = *(const short8*)(zx + (size_t)row * LDZX + tid * 8);
    float g[8];
    float ss = 0.f;
#pragma unroll
    for (int i = 0; i < 8; ++i) {
        float y = bf2f((ushort_t)yv[i]);
        float z = bf2f((ushort_t)zv[i]);
        float sz = z / (1.f + expf(-z));
        float gg = y * sz;
        g[i] = gg;
        ss += gg * gg;
    }
#pragma unroll
    for (int o = 32; o > 0; o >>= 1) ss += __shfl_xor(ss, o);
    __shared__ float wsum[4];
    if ((tid & 63) == 0) wsum[tid >> 6] = ss;
    __syncthreads();
    float tot = wsum[0] + wsum[1] + wsum[2] + wsum[3];
    float scale = rsqrtf(tot * (1.0f / (float)DINNER) + 1e-5f);
    short8 o8;
#pragma unroll
    for (int i = 0; i < 8; ++i)
        o8[i] = (short)f2bf(g[i] * scale * norm_w[tid * 8 + i]);
    *(short8*)(gbuf + (size_t)row * DINNER + tid * 8) = o8;
}

// ---------------- launch ----------------
extern "C" void kernel_launch(void* const* d_in, const int* in_sizes, int n_in,
                              void* d_out, int out_size, void* d_ws, size_t ws_size,
                              hipStream_t stream) {
    const float* x          = (const float*)d_in[0];
    const float* in_proj_w  = (const float*)d_in[1];
    const float* conv_w     = (const float*)d_in[2];
    const float* conv_b     = (const float*)d_in[3];
    const float* dt_bias    = (const float*)d_in[4];
    const float* A_log      = (const float*)d_in[5];
    const float* Dvec       = (const float*)d_in[6];
    const float* norm_w     = (const float*)d_in[7];
    const float* out_proj_w = (const float*)d_in[8];
    float* out = (float*)d_out;

    char* ws = (char*)d_ws;
    size_t off = 0;
    ushort_t* owbf  = (ushort_t*)(ws + off); off += (size_t)KDIM * DINNER * 2;     // 4.2 MB
    ushort_t* zx    = (ushort_t*)(ws + off); off += (size_t)NROWS * LDZX * 2;      // 71.3 MB
    ushort_t* cvb   = (ushort_t*)(ws + off); off += (size_t)NROWS * DCONVD * 2;    // 35.7 MB
    float*    expPb = (float*)(ws + off);    off += (size_t)128 * L_SEQ * 4;       // 1.05 MB
    ushort_t* ybuf  = (ushort_t*)(ws + off); off += (size_t)NROWS * DINNER * 2;    // 33.6 MB
    char* tail = ws + off;
    ushort_t* xbf  = (ushort_t*)tail;
    ushort_t* wbf  = (ushort_t*)(tail + (size_t)NROWS * KDIM * 2);
    ushort_t* Gbuf = (ushort_t*)tail;
    ushort_t* gbuf = (ushort_t*)tail;

    // fused casts (x -> xbf, in_proj_w -> wbf padded, out_proj_w -> owbf)
    fused_cast_kernel<<<(NX4 + NW4 + NO4) / 256, 256, 0, stream>>>(
        x, in_proj_w, out_proj_w, xbf, wbf, owbf);

    // in-proj GEMM: zx[8192][4352] (bf16), 256x256 2-phase + LDS-bounce epilogue
    gemm256_kernel<256, true><<<544, 512, 0, stream>>>(xbf, wbf, zx, KDIM, LDZX, 17);

    // conv + silu (short8-vectorized)
    conv_silu_kernel<<<NROWS * 272 / 256, 256, 0, stream>>>(zx, conv_w, conv_b, cvb);

    // chunked scan: phase A (parallel, MFMA; dt softplus fused)
    chunk_intra_kernel<<<dim3(NCHUNK, NHEADS, 4), 256, 0, stream>>>(
        cvb, zx, dt_bias, A_log, Dvec, ybuf, Gbuf, expPb);
    // phase B1: elementwise state scan (in-place G -> hstates)
    state_scan_kernel<<<dim3(2, NHEADS, 4), 256, 0, stream>>>(Gbuf, expPb);
    // phase B2: inter-chunk contribution (parallel MFMA matmuls)
    y_inter_kernel<<<dim3(NCHUNK - 1, NHEADS, 4), 256, 0, stream>>>(
        cvb, expPb, Gbuf, ybuf);

    // gate + rmsnorm
    gatenorm_kernel<<<NROWS, 256, 0, stream>>>(ybuf, zx, norm_w, gbuf);

    // out-proj GEMM -> d_out (f32), 128x256 2-phase  (grid 256 = 8*32, 1 round)
    gemm256_kernel<128, false><<<256, 512, 0, stream>>>(gbuf, owbf, out, DINNER, KDIM, 4);
}